// Round 6
// baseline (202.037 us; speedup 1.0000x reference)
//
#include <hip/hip_runtime.h>
#include <hip/hip_bf16.h>
#include <cstdint>
#include <math.h>

#define D_MODEL 1024
#define NHEADS  16
#define DK      64
#define BATCH   2
#define SEQ     2048
#define M_TOTAL (BATCH*SEQ)   // 4096 rows
#define NT      (SEQ/64)      // 32 KV tiles

using f32x4  = __attribute__((ext_vector_type(4)))  float;
using f32x16 = __attribute__((ext_vector_type(16))) float;
using s16x8  = __attribute__((ext_vector_type(8)))  short;

#define CSC (0.125f * 1.44269504088896341f)   // (1/sqrt(Dk)) * log2(e)

__device__ __forceinline__ unsigned short bf16r(float f) {
    __hip_bfloat16 h = __float2bfloat16(f);
    return *(unsigned short*)&h;
}
__device__ __forceinline__ uint32_t packbf(float lo, float hi) {
    return (uint32_t)bf16r(lo) | ((uint32_t)bf16r(hi) << 16);
}

// ---------------------------------------------------------------------------
// fp32 -> bf16 elementwise (x). 8 elems/thread, vectorized.
// ---------------------------------------------------------------------------
__global__ __launch_bounds__(256) void conv_x(const float* __restrict__ x,
                                              unsigned short* __restrict__ xb)
{
    const size_t i = ((size_t)blockIdx.x * 256 + threadIdx.x) * 8;
    const float4 a = *(const float4*)(x + i);
    const float4 b = *(const float4*)(x + i + 4);
    ushort4 r0, r1;
    r0.x = bf16r(a.x); r0.y = bf16r(a.y); r0.z = bf16r(a.z); r0.w = bf16r(a.w);
    r1.x = bf16r(b.x); r1.y = bf16r(b.y); r1.z = bf16r(b.z); r1.w = bf16r(b.w);
    *(ushort4*)(xb + i)     = r0;
    *(ushort4*)(xb + i + 4) = r1;
}

// ---------------------------------------------------------------------------
// Transpose + convert: T[n][k] = bf16(W[k][n]), 1024x1024, 32x32 LDS tiles.
// ---------------------------------------------------------------------------
__global__ __launch_bounds__(256) void conv_wt(const float* __restrict__ W0, const float* __restrict__ W1,
                                               const float* __restrict__ W2, const float* __restrict__ W3,
                                               unsigned short* __restrict__ T0, unsigned short* __restrict__ T1,
                                               unsigned short* __restrict__ T2, unsigned short* __restrict__ T3)
{
    const float* W; unsigned short* T;
    switch (blockIdx.z) {
        case 0: W = W0; T = T0; break;
        case 1: W = W1; T = T1; break;
        case 2: W = W2; T = T2; break;
        default: W = W3; T = T3; break;
    }
    __shared__ float tile[32][33];
    const int t  = threadIdx.x;
    const int r  = t >> 3;
    const int c4 = (t & 7) * 4;
    const int k0 = blockIdx.x * 32;
    const int n0 = blockIdx.y * 32;

    const float4 v = *(const float4*)(W + (size_t)(k0 + r) * 1024 + n0 + c4);
    tile[r][c4 + 0] = v.x; tile[r][c4 + 1] = v.y; tile[r][c4 + 2] = v.z; tile[r][c4 + 3] = v.w;
    __syncthreads();
    ushort4 o;
    o.x = bf16r(tile[c4 + 0][r]);
    o.y = bf16r(tile[c4 + 1][r]);
    o.z = bf16r(tile[c4 + 2][r]);
    o.w = bf16r(tile[c4 + 3][r]);
    *(ushort4*)(T + (size_t)(n0 + r) * 1024 + k0 + c4) = o;
}

// ---------------------------------------------------------------------------
// bf16 MFMA GEMM (m97 structure). MODE: 0 = fp32 C, 1 = bf16 C,
// 2 = bf16 C^T (V^T layout: out[n*4096 + m], ushort4 over 4 consecutive m).
// ---------------------------------------------------------------------------
template<int MODE>
__device__ __forceinline__ void gemm_mfma_body(const unsigned short* __restrict__ A,
                                               const unsigned short* __restrict__ Bt,
                                               const float* __restrict__ bias,
                                               void* __restrict__ C,
                                               float oscale)
{
    __shared__ unsigned short As[128 * 64];
    __shared__ unsigned short Bs[128 * 64];

    const int t    = threadIdx.x;
    const int w    = t >> 6;
    const int lane = t & 63;
    const int ln   = lane & 15;
    const int g    = lane >> 4;
    const int wr   = w >> 1, wc = w & 1;
    const int m0   = blockIdx.y * 128;
    const int n0   = blockIdx.x * 128;

    f32x4 acc[4][4];
#pragma unroll
    for (int mi = 0; mi < 4; ++mi)
#pragma unroll
        for (int ni = 0; ni < 4; ++ni)
#pragma unroll
            for (int j = 0; j < 4; ++j) acc[mi][ni][j] = 0.f;

    const int lrow = lane >> 3;
    const int lchk = (lane & 7) ^ lrow;
    const unsigned short* Ag = A  + (size_t)(m0 + w * 32 + lrow) * 1024 + lchk * 8;
    const unsigned short* Bg = Bt + (size_t)(n0 + w * 32 + lrow) * 1024 + lchk * 8;

    for (int kt = 0; kt < 16; ++kt) {
        const int k0 = kt * 64;
#pragma unroll
        for (int i = 0; i < 4; ++i) {
            __builtin_amdgcn_global_load_lds(Ag + (size_t)i * 8 * 1024 + k0,
                                             &As[(w * 32 + i * 8) * 64], 16, 0, 0);
            __builtin_amdgcn_global_load_lds(Bg + (size_t)i * 8 * 1024 + k0,
                                             &Bs[(w * 32 + i * 8) * 64], 16, 0, 0);
        }
        __syncthreads();

#pragma unroll
        for (int ks = 0; ks < 2; ++ks) {
            s16x8 af[4], bf[4];
#pragma unroll
            for (int mi = 0; mi < 4; ++mi) {
                const int row = wr * 64 + mi * 16 + ln;
                af[mi] = *(const s16x8*)((const char*)As + row * 128 +
                                         (((ks * 4 + g) ^ (ln & 7)) * 16));
            }
#pragma unroll
            for (int ni = 0; ni < 4; ++ni) {
                const int row = wc * 64 + ni * 16 + ln;
                bf[ni] = *(const s16x8*)((const char*)Bs + row * 128 +
                                         (((ks * 4 + g) ^ (ln & 7)) * 16));
            }
#pragma unroll
            for (int mi = 0; mi < 4; ++mi)
#pragma unroll
                for (int ni = 0; ni < 4; ++ni)
                    acc[mi][ni] = __builtin_amdgcn_mfma_f32_16x16x32_bf16(
                        af[mi], bf[ni], acc[mi][ni], 0, 0, 0);
        }
        __syncthreads();
    }

#pragma unroll
    for (int ni = 0; ni < 4; ++ni) {
        const int n = n0 + wc * 64 + ni * 16 + ln;
        const float bn = bias[n];
#pragma unroll
        for (int mi = 0; mi < 4; ++mi) {
            const int m = m0 + wr * 64 + mi * 16 + g * 4;
            if constexpr (MODE == 2) {
                ushort4 pk;
                pk.x = bf16r((acc[mi][ni][0] + bn) * oscale);
                pk.y = bf16r((acc[mi][ni][1] + bn) * oscale);
                pk.z = bf16r((acc[mi][ni][2] + bn) * oscale);
                pk.w = bf16r((acc[mi][ni][3] + bn) * oscale);
                *(ushort4*)((unsigned short*)C + (size_t)n * 4096 + m) = pk;
            } else {
#pragma unroll
                for (int j = 0; j < 4; ++j) {
                    const float v = (acc[mi][ni][j] + bn) * oscale;
                    if constexpr (MODE == 1)
                        ((unsigned short*)C)[(size_t)(m + j) * 1024 + n] = bf16r(v);
                    else
                        ((float*)C)[(size_t)(m + j) * 1024 + n] = v;
                }
            }
        }
    }
}

__global__ __launch_bounds__(256) void qkv_mfma(const unsigned short* __restrict__ xb,
                                                const unsigned short* __restrict__ Wqt, const float* __restrict__ bq,
                                                const unsigned short* __restrict__ Wkt, const float* __restrict__ bk,
                                                const unsigned short* __restrict__ Wvt, const float* __restrict__ bv,
                                                unsigned short* __restrict__ Q,
                                                unsigned short* __restrict__ K,
                                                unsigned short* __restrict__ Vt)
{
    if (blockIdx.z == 0)      gemm_mfma_body<1>(xb, Wqt, bq, Q,  CSC);   // Q pre-scaled
    else if (blockIdx.z == 1) gemm_mfma_body<1>(xb, Wkt, bk, K,  1.0f);
    else                      gemm_mfma_body<2>(xb, Wvt, bv, Vt, 1.0f);  // V^T
}

__global__ __launch_bounds__(256) void oproj_mfma(const unsigned short* __restrict__ Ab,
                                                  const unsigned short* __restrict__ Wot,
                                                  const float* __restrict__ bo,
                                                  float* __restrict__ C)
{
    gemm_mfma_body<0>(Ab, Wot, bo, C, 1.0f);
}

// ---------------------------------------------------------------------------
// Flash attention, mfma_f32_32x32x16_bf16, ZERO LDS / ZERO barriers.
// Block: 256 thr = 4 independent waves x 32 q-rows. Grid (16, 32).
// All operand fragments are per-lane contiguous 16B global loads:
//   QK^T A-frag: K[kvb + q32 (+32)][16ks+8hi..+7]         (natural K layout)
//   PV   A-frag: V^T[q32 (+32)][kvb_local + 16ks+8hi..+7] (Vt layout [n][m])
// Fragments are reloaded in place for tile kt+1 right after their last use
// in tile kt (WAR-ordered; ~1 tile of compute covers L2 latency; KV is
// L2/L3-resident). Softmax lane-local (exp2 domain), pack via verified
// __shfl_xor(32) + slot-select (round 5).
// ---------------------------------------------------------------------------
__global__ __launch_bounds__(256, 2) void attn_mfma(const unsigned short* __restrict__ Qb,
                                                    const unsigned short* __restrict__ Kb,
                                                    const unsigned short* __restrict__ Vt,
                                                    unsigned short* __restrict__ O)
{
    const int t   = threadIdx.x;
    const int wid = t >> 6;
    const int l   = t & 63;
    const int q32 = l & 31;
    const int hi  = l >> 5;

    const int bh = blockIdx.y;
    const int b  = bh >> 4;
    const int h  = bh & 15;
    const int qbase = blockIdx.x * 128 + wid * 32;
    const size_t qrow = (size_t)(b * SEQ + qbase + q32);
    const size_t kv0  = (size_t)(b * SEQ);

    // Q resident (B-frags): qf[ks] = Q[qrow][d = 16ks + 8hi .. +7]
    s16x8 qf[4];
    {
        const unsigned short* qp = Qb + qrow * D_MODEL + h * DK + 8 * hi;
#pragma unroll
        for (int ks = 0; ks < 4; ++ks) qf[ks] = *(const s16x8*)(qp + 16 * ks);
    }

    // per-lane fragment base pointers
    const unsigned short* KA = Kb + (kv0 + q32) * D_MODEL + h * DK + 8 * hi;
    const unsigned short* KB = KA + (size_t)32 * D_MODEL;
    const unsigned short* VA = Vt + (size_t)(h * DK + q32) * 4096 + b * SEQ + 8 * hi;
    const unsigned short* VB = VA + (size_t)32 * 4096;

    s16x8 kf[8], vf[8];
#pragma unroll
    for (int ks = 0; ks < 4; ++ks) {
        kf[ks]     = *(const s16x8*)(KA + 16 * ks);
        kf[4 + ks] = *(const s16x8*)(KB + 16 * ks);
        vf[ks]     = *(const s16x8*)(VA + 16 * ks);
        vf[4 + ks] = *(const s16x8*)(VB + 16 * ks);
    }

    f32x16 ot0, ot1;   // O^T accum: d = crow(r,hi) + 32*{0,1}, col q = q32
#pragma unroll
    for (int i = 0; i < 16; ++i) { ot0[i] = 0.f; ot1[i] = 0.f; }
    float mrun = -INFINITY, lsum = 0.f;

    for (int kt = 0; kt < NT; ++kt) {
        // ---- QK^T ----
        f32x16 s0, s1;
#pragma unroll
        for (int i = 0; i < 16; ++i) { s0[i] = 0.f; s1[i] = 0.f; }
#pragma unroll
        for (int ks = 0; ks < 4; ++ks) {
            s0 = __builtin_amdgcn_mfma_f32_32x32x16_bf16(kf[ks],     qf[ks], s0, 0, 0, 0);
            s1 = __builtin_amdgcn_mfma_f32_32x32x16_bf16(kf[4 + ks], qf[ks], s1, 0, 0, 0);
        }

        // reload K frags in place for tile kt+1 (hides under softmax+PV)
        const int ktn = (kt + 1 < NT) ? kt + 1 : NT - 1;
        {
            const size_t ko = (size_t)ktn * 64 * D_MODEL;
#pragma unroll
            for (int ks = 0; ks < 4; ++ks) {
                kf[ks]     = *(const s16x8*)(KA + ko + 16 * ks);
                kf[4 + ks] = *(const s16x8*)(KB + ko + 16 * ks);
            }
        }

        // ---- online softmax (scores pre-scaled into exp2 domain) ----
        float c0 = s0[0], c1 = s0[1], c2 = s0[2], c3 = s0[3];
#pragma unroll
        for (int i = 1; i < 4; ++i) {
            c0 = fmaxf(c0, s0[4 * i + 0]); c1 = fmaxf(c1, s0[4 * i + 1]);
            c2 = fmaxf(c2, s0[4 * i + 2]); c3 = fmaxf(c3, s0[4 * i + 3]);
        }
#pragma unroll
        for (int i = 0; i < 4; ++i) {
            c0 = fmaxf(c0, s1[4 * i + 0]); c1 = fmaxf(c1, s1[4 * i + 1]);
            c2 = fmaxf(c2, s1[4 * i + 2]); c3 = fmaxf(c3, s1[4 * i + 3]);
        }
        float mc = fmaxf(fmaxf(c0, c1), fmaxf(c2, c3));
        mc = fmaxf(mc, __shfl_xor(mc, 32));   // full 64-key row max

        if (!__all(mc - mrun <= 8.0f)) {      // defer-max: rescale on growth only
            const float mnew = fmaxf(mrun, mc);
            const float r = exp2f(mrun - mnew);
            lsum *= r;
#pragma unroll
            for (int i = 0; i < 16; ++i) { ot0[i] *= r; ot1[i] *= r; }
            mrun = mnew;
        }

        float l0 = 0.f, l1 = 0.f, l2 = 0.f, l3 = 0.f;
#pragma unroll
        for (int i = 0; i < 4; ++i) {
            s0[4 * i + 0] = exp2f(s0[4 * i + 0] - mrun); l0 += s0[4 * i + 0];
            s0[4 * i + 1] = exp2f(s0[4 * i + 1] - mrun); l1 += s0[4 * i + 1];
            s0[4 * i + 2] = exp2f(s0[4 * i + 2] - mrun); l2 += s0[4 * i + 2];
            s0[4 * i + 3] = exp2f(s0[4 * i + 3] - mrun); l3 += s0[4 * i + 3];
            s1[4 * i + 0] = exp2f(s1[4 * i + 0] - mrun); l0 += s1[4 * i + 0];
            s1[4 * i + 1] = exp2f(s1[4 * i + 1] - mrun); l1 += s1[4 * i + 1];
            s1[4 * i + 2] = exp2f(s1[4 * i + 2] - mrun); l2 += s1[4 * i + 2];
            s1[4 * i + 3] = exp2f(s1[4 * i + 3] - mrun); l3 += s1[4 * i + 3];
        }
        lsum += (l0 + l1) + (l2 + l3);

        // ---- pack P -> PV B-frags (verified round-5 mapping) ----
        s16x8 pf[4];
#pragma unroll
        for (int half = 0; half < 2; ++half) {
            const f32x16& sv = half ? s1 : s0;
            uint32_t W[8], Y[8];
#pragma unroll
            for (int j = 0; j < 8; ++j) W[j] = packbf(sv[2 * j], sv[2 * j + 1]);
#pragma unroll
            for (int j = 0; j < 8; ++j) Y[j] = __shfl_xor(W[j], 32);
            union { uint32_t u[4]; s16x8 v; } F0, F1;
            F0.u[0] = hi ? Y[2] : W[0];
            F0.u[1] = hi ? Y[3] : W[1];
            F0.u[2] = hi ? W[2] : Y[0];
            F0.u[3] = hi ? W[3] : Y[1];
            F1.u[0] = hi ? Y[6] : W[4];
            F1.u[1] = hi ? Y[7] : W[5];
            F1.u[2] = hi ? W[6] : Y[4];
            F1.u[3] = hi ? W[7] : Y[5];
            pf[2 * half]     = F0.v;
            pf[2 * half + 1] = F1.v;
        }

        // ---- PV: O^T += V^T · P^T ----
#pragma unroll
        for (int ks = 0; ks < 4; ++ks) {
            ot0 = __builtin_amdgcn_mfma_f32_32x32x16_bf16(vf[ks],     pf[ks], ot0, 0, 0, 0);
            ot1 = __builtin_amdgcn_mfma_f32_32x32x16_bf16(vf[4 + ks], pf[ks], ot1, 0, 0, 0);
        }

        // reload V frags in place for tile kt+1 (hides under next QK+softmax)
        {
            const size_t vo = (size_t)ktn * 64;
#pragma unroll
            for (int ks = 0; ks < 4; ++ks) {
                vf[ks]     = *(const s16x8*)(VA + vo + 16 * ks);
                vf[4 + ks] = *(const s16x8*)(VB + vo + 16 * ks);
            }
        }
    }

    // ---- normalize + store bf16 (d = 8j + 4hi + i + 32*dtile) ----
    const float inv = 1.0f / (lsum + __shfl_xor(lsum, 32));
    unsigned short* op = O + qrow * D_MODEL + h * DK;
#pragma unroll
    for (int j = 0; j < 4; ++j) {
        ushort4 st0, st1;
        st0.x = bf16r(ot0[4 * j + 0] * inv);
        st0.y = bf16r(ot0[4 * j + 1] * inv);
        st0.z = bf16r(ot0[4 * j + 2] * inv);
        st0.w = bf16r(ot0[4 * j + 3] * inv);
        st1.x = bf16r(ot1[4 * j + 0] * inv);
        st1.y = bf16r(ot1[4 * j + 1] * inv);
        st1.z = bf16r(ot1[4 * j + 2] * inv);
        st1.w = bf16r(ot1[4 * j + 3] * inv);
        *(ushort4*)(op + 8 * j + 4 * hi)      = st0;
        *(ushort4*)(op + 32 + 8 * j + 4 * hi) = st1;
    }
}

// ---------------------------------------------------------------------------
// ws layout (bf16): xb 8MB | Wqt|Wkt|Wvt|Wot 2MB ea | Qb 8MB | Kb 8MB |
// Vt 8MB (layout [n=1024][m=4096]) | Ab 8MB = 48MB. All written before read;
// attn's clamped prefetch never reads past Vt+8MB+4KB (inside Ab) or
// Kb+8MB+128KB (inside Vt) -> always valid ws memory.
// ---------------------------------------------------------------------------
extern "C" void kernel_launch(void* const* d_in, const int* in_sizes, int n_in,
                              void* d_out, int out_size, void* d_ws, size_t ws_size,
                              hipStream_t stream)
{
    const float* x  = (const float*)d_in[0];
    const float* Wq = (const float*)d_in[1];
    const float* bq = (const float*)d_in[2];
    const float* Wk = (const float*)d_in[3];
    const float* bk = (const float*)d_in[4];
    const float* Wv = (const float*)d_in[5];
    const float* bv = (const float*)d_in[6];
    const float* Wo = (const float*)d_in[7];
    const float* bo = (const float*)d_in[8];

    float* out = (float*)d_out;

    const size_t mat  = (size_t)M_TOTAL * D_MODEL;
    const size_t wmat = (size_t)D_MODEL * D_MODEL;
    unsigned short* xb  = (unsigned short*)d_ws;
    unsigned short* Wqt = xb  + mat;
    unsigned short* Wkt = Wqt + wmat;
    unsigned short* Wvt = Wkt + wmat;
    unsigned short* Wot = Wvt + wmat;
    unsigned short* Qb  = Wot + wmat;
    unsigned short* Kb  = Qb  + mat;
    unsigned short* Vt  = Kb  + mat;
    unsigned short* Ab  = Vt  + mat;

    conv_x<<<dim3(2048), 256, 0, stream>>>(x, xb);
    conv_wt<<<dim3(32, 32, 4), 256, 0, stream>>>(Wq, Wk, Wv, Wo, Wqt, Wkt, Wvt, Wot);

    qkv_mfma<<<dim3(8, 32, 3), 256, 0, stream>>>(xb, Wqt, bq, Wkt, bk, Wvt, bv, Qb, Kb, Vt);

    attn_mfma<<<dim3(SEQ / 128, BATCH * NHEADS), 256, 0, stream>>>(Qb, Kb, Vt, Ab);

    oproj_mfma<<<dim3(8, 32), 256, 0, stream>>>(Ab, Wot, bo, out);
}

// Round 7
// 151.541 us; speedup vs baseline: 1.3332x; 1.3332x over previous
//
#include <hip/hip_runtime.h>
#include <hip/hip_bf16.h>
#include <cstdint>
#include <math.h>

#define D_MODEL 1024
#define NHEADS  16
#define DK      64
#define BATCH   2
#define SEQ     2048
#define M_TOTAL (BATCH*SEQ)   // 4096 rows
#define NSPLIT  2
#define NTS     (SEQ/64/NSPLIT)   // 16 tiles per split

using f32x4  = __attribute__((ext_vector_type(4)))  float;
using f32x16 = __attribute__((ext_vector_type(16))) float;
using s16x8  = __attribute__((ext_vector_type(8)))  short;

#define CSC (0.125f * 1.44269504088896341f)   // (1/sqrt(Dk)) * log2(e)

__device__ __forceinline__ unsigned short bf16r(float f) {
    __hip_bfloat16 h = __float2bfloat16(f);
    return *(unsigned short*)&h;
}
// HW packed convert (T12 recipe): lo -> bits[15:0], hi -> bits[31:16], RNE
__device__ __forceinline__ uint32_t cvtpk(float lo, float hi) {
    uint32_t r;
    asm("v_cvt_pk_bf16_f32 %0, %1, %2" : "=v"(r) : "v"(lo), "v"(hi));
    return r;
}
__device__ __forceinline__ float b2f(unsigned short u) {
    uint32_t x = (uint32_t)u << 16;
    float f;
    __builtin_memcpy(&f, &x, 4);
    return f;
}

// ---------------------------------------------------------------------------
// fp32 -> bf16 elementwise (x). 8 elems/thread, vectorized.
// ---------------------------------------------------------------------------
__global__ __launch_bounds__(256) void conv_x(const float* __restrict__ x,
                                              unsigned short* __restrict__ xb)
{
    const size_t i = ((size_t)blockIdx.x * 256 + threadIdx.x) * 8;
    const float4 a = *(const float4*)(x + i);
    const float4 b = *(const float4*)(x + i + 4);
    ushort4 r0, r1;
    r0.x = bf16r(a.x); r0.y = bf16r(a.y); r0.z = bf16r(a.z); r0.w = bf16r(a.w);
    r1.x = bf16r(b.x); r1.y = bf16r(b.y); r1.z = bf16r(b.z); r1.w = bf16r(b.w);
    *(ushort4*)(xb + i)     = r0;
    *(ushort4*)(xb + i + 4) = r1;
}

// ---------------------------------------------------------------------------
// Transpose + convert: T[n][k] = bf16(W[k][n]), 1024x1024, 32x32 LDS tiles.
// ---------------------------------------------------------------------------
__global__ __launch_bounds__(256) void conv_wt(const float* __restrict__ W0, const float* __restrict__ W1,
                                               const float* __restrict__ W2, const float* __restrict__ W3,
                                               unsigned short* __restrict__ T0, unsigned short* __restrict__ T1,
                                               unsigned short* __restrict__ T2, unsigned short* __restrict__ T3)
{
    const float* W; unsigned short* T;
    switch (blockIdx.z) {
        case 0: W = W0; T = T0; break;
        case 1: W = W1; T = T1; break;
        case 2: W = W2; T = T2; break;
        default: W = W3; T = T3; break;
    }
    __shared__ float tile[32][33];
    const int t  = threadIdx.x;
    const int r  = t >> 3;
    const int c4 = (t & 7) * 4;
    const int k0 = blockIdx.x * 32;
    const int n0 = blockIdx.y * 32;

    const float4 v = *(const float4*)(W + (size_t)(k0 + r) * 1024 + n0 + c4);
    tile[r][c4 + 0] = v.x; tile[r][c4 + 1] = v.y; tile[r][c4 + 2] = v.z; tile[r][c4 + 3] = v.w;
    __syncthreads();
    ushort4 o;
    o.x = bf16r(tile[c4 + 0][r]);
    o.y = bf16r(tile[c4 + 1][r]);
    o.z = bf16r(tile[c4 + 2][r]);
    o.w = bf16r(tile[c4 + 3][r]);
    *(ushort4*)(T + (size_t)(n0 + r) * 1024 + k0 + c4) = o;
}

// ---------------------------------------------------------------------------
// bf16 MFMA GEMM (m97 structure), optional output scale.
// ---------------------------------------------------------------------------
template<int OUT_BF16>
__device__ __forceinline__ void gemm_mfma_body(const unsigned short* __restrict__ A,
                                               const unsigned short* __restrict__ Bt,
                                               const float* __restrict__ bias,
                                               void* __restrict__ C,
                                               float oscale)
{
    __shared__ unsigned short As[128 * 64];
    __shared__ unsigned short Bs[128 * 64];

    const int t    = threadIdx.x;
    const int w    = t >> 6;
    const int lane = t & 63;
    const int ln   = lane & 15;
    const int g    = lane >> 4;
    const int wr   = w >> 1, wc = w & 1;
    const int m0   = blockIdx.y * 128;
    const int n0   = blockIdx.x * 128;

    f32x4 acc[4][4];
#pragma unroll
    for (int mi = 0; mi < 4; ++mi)
#pragma unroll
        for (int ni = 0; ni < 4; ++ni)
#pragma unroll
            for (int j = 0; j < 4; ++j) acc[mi][ni][j] = 0.f;

    const int lrow = lane >> 3;
    const int lchk = (lane & 7) ^ lrow;
    const unsigned short* Ag = A  + (size_t)(m0 + w * 32 + lrow) * 1024 + lchk * 8;
    const unsigned short* Bg = Bt + (size_t)(n0 + w * 32 + lrow) * 1024 + lchk * 8;

    for (int kt = 0; kt < 16; ++kt) {
        const int k0 = kt * 64;
#pragma unroll
        for (int i = 0; i < 4; ++i) {
            __builtin_amdgcn_global_load_lds(Ag + (size_t)i * 8 * 1024 + k0,
                                             &As[(w * 32 + i * 8) * 64], 16, 0, 0);
            __builtin_amdgcn_global_load_lds(Bg + (size_t)i * 8 * 1024 + k0,
                                             &Bs[(w * 32 + i * 8) * 64], 16, 0, 0);
        }
        __syncthreads();

#pragma unroll
        for (int ks = 0; ks < 2; ++ks) {
            s16x8 af[4], bf[4];
#pragma unroll
            for (int mi = 0; mi < 4; ++mi) {
                const int row = wr * 64 + mi * 16 + ln;
                af[mi] = *(const s16x8*)((const char*)As + row * 128 +
                                         (((ks * 4 + g) ^ (ln & 7)) * 16));
            }
#pragma unroll
            for (int ni = 0; ni < 4; ++ni) {
                const int row = wc * 64 + ni * 16 + ln;
                bf[ni] = *(const s16x8*)((const char*)Bs + row * 128 +
                                         (((ks * 4 + g) ^ (ln & 7)) * 16));
            }
#pragma unroll
            for (int mi = 0; mi < 4; ++mi)
#pragma unroll
                for (int ni = 0; ni < 4; ++ni)
                    acc[mi][ni] = __builtin_amdgcn_mfma_f32_16x16x32_bf16(
                        af[mi], bf[ni], acc[mi][ni], 0, 0, 0);
        }
        __syncthreads();
    }

#pragma unroll
    for (int ni = 0; ni < 4; ++ni) {
        const int n = n0 + wc * 64 + ni * 16 + ln;
        const float bn = bias[n];
#pragma unroll
        for (int mi = 0; mi < 4; ++mi) {
            const int m = m0 + wr * 64 + mi * 16 + g * 4;
#pragma unroll
            for (int j = 0; j < 4; ++j) {
                const float v = (acc[mi][ni][j] + bn) * oscale;
                if constexpr (OUT_BF16)
                    ((unsigned short*)C)[(size_t)(m + j) * 1024 + n] = bf16r(v);
                else
                    ((float*)C)[(size_t)(m + j) * 1024 + n] = v;
            }
        }
    }
}

__global__ __launch_bounds__(256) void qkv_mfma(const unsigned short* __restrict__ xb,
                                                const unsigned short* __restrict__ Wqt, const float* __restrict__ bq,
                                                const unsigned short* __restrict__ Wkt, const float* __restrict__ bk,
                                                const unsigned short* __restrict__ Wvt, const float* __restrict__ bv,
                                                unsigned short* __restrict__ Q,
                                                unsigned short* __restrict__ K,
                                                unsigned short* __restrict__ V)
{
    if (blockIdx.z == 0)      gemm_mfma_body<1>(xb, Wqt, bq, Q, CSC);   // Q pre-scaled
    else if (blockIdx.z == 1) gemm_mfma_body<1>(xb, Wkt, bk, K, 1.0f);
    else                      gemm_mfma_body<1>(xb, Wvt, bv, V, 1.0f);
}

__global__ __launch_bounds__(256) void oproj_mfma(const unsigned short* __restrict__ Ab,
                                                  const unsigned short* __restrict__ Wot,
                                                  const float* __restrict__ bo,
                                                  float* __restrict__ C)
{
    gemm_mfma_body<0>(Ab, Wot, bo, C, 1.0f);
}

// ---------------------------------------------------------------------------
// Flash attention, mfma_f32_32x32x16_bf16, KV-split=2 (round-5 body).
// Grid (16, 32, 2): block = 4 waves x 32 q-rows = 128 q of one (b,h), over
// keys [sp*1024, sp*1024+1024). Writes unnormalized bf16 O^T partials +
// per-row (m, l); attn_combine merges the two splits.
// ---------------------------------------------------------------------------
__global__ __launch_bounds__(256, 2) void attn_mfma(const unsigned short* __restrict__ Qb,
                                                    const unsigned short* __restrict__ Kb,
                                                    const unsigned short* __restrict__ Vb,
                                                    unsigned short* __restrict__ Opart,
                                                    float2* __restrict__ ml)
{
    __shared__ unsigned short Klds [64 * 64];   // [key][d], chunk ^= key&7
    __shared__ unsigned short Vtlds[64 * 64];   // [d][key], chunk ^= d&7

    const int t   = threadIdx.x;
    const int wid = t >> 6;
    const int l   = t & 63;
    const int q32 = l & 31;
    const int hi  = l >> 5;

    const int bh = blockIdx.y;
    const int b  = bh >> 4;
    const int h  = bh & 15;
    const int sp = blockIdx.z;
    const int qbase = blockIdx.x * 128 + wid * 32;
    const size_t qrow = (size_t)(b * SEQ + qbase + q32);
    const size_t kv0  = (size_t)(b * SEQ) + (size_t)sp * (SEQ / NSPLIT);

    // Q resident (B-frags): qf[ks] = Q[qrow][d = 16ks + 8hi .. +7]
    s16x8 qf[4];
    {
        const unsigned short* qp = Qb + qrow * D_MODEL + h * DK + 8 * hi;
#pragma unroll
        for (int ks = 0; ks < 4; ++ks) qf[ks] = *(const s16x8*)(qp + 16 * ks);
    }

    f32x16 ot0, ot1;   // O^T accum: d = crow(r,hi) + 32*{0,1}, col q = q32
#pragma unroll
    for (int i = 0; i < 16; ++i) { ot0[i] = 0.f; ot1[i] = 0.f; }
    float mrun = -INFINITY, lsum = 0.f;

    // staging mappings (block-wide, 256 threads, 64 keys x 64 d)
    const int skey = t >> 3;
    const int sc8  = t & 7;
    const int vk2  = 2 * (t & 31);
    const int vd0  = 8 * (t >> 5);
    const unsigned short* Kg = Kb + (kv0 + skey) * D_MODEL + h * DK + 8 * sc8;
    const unsigned short* Vg = Vb + (kv0 + vk2) * D_MODEL + h * DK + vd0;
    char* const kw0 = (char*)Klds + skey * 128        + 16 * (sc8 ^ (skey & 7));
    char* const kw1 = (char*)Klds + (skey + 32) * 128 + 16 * (sc8 ^ (skey & 7));

    s16x8 kr0, kr1, vr0, vr1;

    auto write_stage = [&]() {
        *(s16x8*)kw0 = kr0;
        *(s16x8*)kw1 = kr1;
#pragma unroll
        for (int i = 0; i < 8; ++i) {
            const int d = vd0 + i;
            const uint32_t val = (uint32_t)(unsigned short)vr0[i] |
                                 ((uint32_t)(unsigned short)vr1[i] << 16);
            *(uint32_t*)((char*)Vtlds + d * 128 + 16 * ((vk2 >> 3) ^ (d & 7)) + (vk2 & 7) * 2) = val;
        }
    };

    // prologue: stage tile 0
    kr0 = *(const s16x8*)(Kg);
    kr1 = *(const s16x8*)(Kg + (size_t)32 * D_MODEL);
    vr0 = *(const s16x8*)(Vg);
    vr1 = *(const s16x8*)(Vg + D_MODEL);
    write_stage();
    __syncthreads();

    for (int kt = 0; kt < NTS; ++kt) {
        // issue next tile's global loads (consumed after barrier 1)
        if (kt < NTS - 1) {
            const size_t off = (size_t)(kt + 1) * 64 * D_MODEL;
            kr0 = *(const s16x8*)(Kg + off);
            kr1 = *(const s16x8*)(Kg + off + (size_t)32 * D_MODEL);
            vr0 = *(const s16x8*)(Vg + off);
            vr1 = *(const s16x8*)(Vg + off + D_MODEL);
        }

        // ---- QK^T ----
        f32x16 s0, s1;
#pragma unroll
        for (int i = 0; i < 16; ++i) { s0[i] = 0.f; s1[i] = 0.f; }
#pragma unroll
        for (int ks = 0; ks < 4; ++ks) {
            const int c = hi + 2 * ks;
            const s16x8 a0 = *(const s16x8*)((char*)Klds + q32 * 128 +
                                             16 * (c ^ (q32 & 7)));
            const s16x8 a1 = *(const s16x8*)((char*)Klds + (q32 + 32) * 128 +
                                             16 * (c ^ (q32 & 7)));
            s0 = __builtin_amdgcn_mfma_f32_32x32x16_bf16(a0, qf[ks], s0, 0, 0, 0);
            s1 = __builtin_amdgcn_mfma_f32_32x32x16_bf16(a1, qf[ks], s1, 0, 0, 0);
        }

        // ---- online softmax (scores already in exp2 domain) ----
        float mc = s0[0];
#pragma unroll
        for (int i = 1; i < 16; ++i) mc = fmaxf(mc, s0[i]);
#pragma unroll
        for (int i = 0; i < 16; ++i) mc = fmaxf(mc, s1[i]);
        mc = fmaxf(mc, __shfl_xor(mc, 32));   // full 64-key row max

        if (!__all(mc - mrun <= 8.0f)) {      // defer-max: rescale on growth only
            const float mnew = fmaxf(mrun, mc);
            const float r = exp2f(mrun - mnew);
            lsum *= r;
#pragma unroll
            for (int i = 0; i < 16; ++i) { ot0[i] *= r; ot1[i] *= r; }
            mrun = mnew;
        }

        float ls = 0.f;
#pragma unroll
        for (int i = 0; i < 16; ++i) {
            s0[i] = exp2f(s0[i] - mrun); ls += s0[i];
            s1[i] = exp2f(s1[i] - mrun); ls += s1[i];
        }
        lsum += ls;

        // ---- pack P -> PV B-frags (round-5 mapping, cvtpk primitive) ----
        s16x8 pf[4];
#pragma unroll
        for (int half = 0; half < 2; ++half) {
            const f32x16& sv = half ? s1 : s0;
            uint32_t W[8], Y[8];
#pragma unroll
            for (int j = 0; j < 8; ++j) W[j] = cvtpk(sv[2 * j], sv[2 * j + 1]);
#pragma unroll
            for (int j = 0; j < 8; ++j) Y[j] = __shfl_xor(W[j], 32);
            union { uint32_t u[4]; s16x8 v; } F0, F1;
            F0.u[0] = hi ? Y[2] : W[0];
            F0.u[1] = hi ? Y[3] : W[1];
            F0.u[2] = hi ? W[2] : Y[0];
            F0.u[3] = hi ? W[3] : Y[1];
            F1.u[0] = hi ? Y[6] : W[4];
            F1.u[1] = hi ? Y[7] : W[5];
            F1.u[2] = hi ? W[6] : Y[4];
            F1.u[3] = hi ? W[7] : Y[5];
            pf[2 * half]     = F0.v;
            pf[2 * half + 1] = F1.v;
        }

        // ---- PV: O^T += V^T · P^T ----
#pragma unroll
        for (int ks = 0; ks < 4; ++ks) {
            const int c = hi + 2 * ks;
            const s16x8 av0 = *(const s16x8*)((char*)Vtlds + q32 * 128 +
                                              16 * (c ^ (q32 & 7)));
            const s16x8 av1 = *(const s16x8*)((char*)Vtlds + (q32 + 32) * 128 +
                                              16 * (c ^ (q32 & 7)));
            ot0 = __builtin_amdgcn_mfma_f32_32x32x16_bf16(av0, pf[ks], ot0, 0, 0, 0);
            ot1 = __builtin_amdgcn_mfma_f32_32x32x16_bf16(av1, pf[ks], ot1, 0, 0, 0);
        }

        __syncthreads();                 // all waves done reading K/V LDS
        if (kt < NTS - 1) write_stage();
        __syncthreads();                 // next tile visible
    }

    // ---- store unnormalized bf16 partials + (m, l) ----
    const float ltot = lsum + __shfl_xor(lsum, 32);
    const size_t prow = (size_t)bh * SEQ + qbase + q32;   // (b,h,s) row index
    if (hi == 0)
        ml[(size_t)sp * (BATCH * NHEADS * SEQ) + prow] = make_float2(mrun, ltot);

    unsigned short* op = Opart + (size_t)sp * ((size_t)BATCH * NHEADS * SEQ * DK)
                               + prow * DK;
#pragma unroll
    for (int j = 0; j < 4; ++j) {
        uint2 st0, st1;
        st0.x = cvtpk(ot0[4 * j + 0], ot0[4 * j + 1]);
        st0.y = cvtpk(ot0[4 * j + 2], ot0[4 * j + 3]);
        st1.x = cvtpk(ot1[4 * j + 0], ot1[4 * j + 1]);
        st1.y = cvtpk(ot1[4 * j + 2], ot1[4 * j + 3]);
        *(uint2*)(op + 8 * j + 4 * hi)      = st0;
        *(uint2*)(op + 32 + 8 * j + 4 * hi) = st1;
    }
}

// ---------------------------------------------------------------------------
// Merge the two KV-splits: O = (w0*Ot0 + w1*Ot1) / (w0*l0 + w1*l1).
// tid -> (row = bh*SEQ + s, 8 d's). Opart reads are fully linear.
// ---------------------------------------------------------------------------
__global__ __launch_bounds__(256) void attn_combine(const unsigned short* __restrict__ Opart,
                                                    const float2* __restrict__ ml,
                                                    unsigned short* __restrict__ Ab)
{
    const int tid = blockIdx.x * 256 + threadIdx.x;
    const int row = tid >> 3;             // 0 .. 65535
    const int d0  = (tid & 7) * 8;
    const size_t NROW = (size_t)BATCH * NHEADS * SEQ;

    const float2 a = ml[row];
    const float2 c = ml[NROW + row];
    const float mm = fmaxf(a.x, c.x);
    const float w0 = exp2f(a.x - mm);
    const float w1 = exp2f(c.x - mm);
    const float rinv = 1.0f / (w0 * a.y + w1 * c.y);

    const size_t src = (size_t)row * DK + d0;
    const ushort4 u0 = *(const ushort4*)(Opart + src);
    const ushort4 u1 = *(const ushort4*)(Opart + src + 4);
    const ushort4 v0 = *(const ushort4*)(Opart + NROW * DK + src);
    const ushort4 v1 = *(const ushort4*)(Opart + NROW * DK + src + 4);

    const int bh = row >> 11, s = row & 2047;
    const int b = bh >> 4, h = bh & 15;
    unsigned short* dst = Ab + ((size_t)(b * SEQ + s)) * D_MODEL + h * DK + d0;

    ushort4 o0, o1;
    o0.x = bf16r((w0 * b2f(u0.x) + w1 * b2f(v0.x)) * rinv);
    o0.y = bf16r((w0 * b2f(u0.y) + w1 * b2f(v0.y)) * rinv);
    o0.z = bf16r((w0 * b2f(u0.z) + w1 * b2f(v0.z)) * rinv);
    o0.w = bf16r((w0 * b2f(u0.w) + w1 * b2f(v0.w)) * rinv);
    o1.x = bf16r((w0 * b2f(u1.x) + w1 * b2f(v1.x)) * rinv);
    o1.y = bf16r((w0 * b2f(u1.y) + w1 * b2f(v1.y)) * rinv);
    o1.z = bf16r((w0 * b2f(u1.z) + w1 * b2f(v1.z)) * rinv);
    o1.w = bf16r((w0 * b2f(u1.w) + w1 * b2f(v1.w)) * rinv);
    *(ushort4*)(dst)     = o0;
    *(ushort4*)(dst + 4) = o1;
}

// ---------------------------------------------------------------------------
// ws layout (64 MB total, proven safe in round 1):
//   [0,8M)   xb (bf16)          -- dead after qkv; first 1MB reused for ml
//   [8,16M)  Wqt|Wkt|Wvt|Wot
//   [16,24M) Qb | [24,32M) Kb | [32,40M) Vb | [40,48M) Ab
//   [48,64M) Opart (2 splits x 8MB bf16)
//   ml (2 x 512KB float2) overlaid at [0,1M) -- written by attn AFTER qkv
//   consumed xb; rewritten every launch (replay-safe).
// ---------------------------------------------------------------------------
extern "C" void kernel_launch(void* const* d_in, const int* in_sizes, int n_in,
                              void* d_out, int out_size, void* d_ws, size_t ws_size,
                              hipStream_t stream)
{
    const float* x  = (const float*)d_in[0];
    const float* Wq = (const float*)d_in[1];
    const float* bq = (const float*)d_in[2];
    const float* Wk = (const float*)d_in[3];
    const float* bk = (const float*)d_in[4];
    const float* Wv = (const float*)d_in[5];
    const float* bv = (const float*)d_in[6];
    const float* Wo = (const float*)d_in[7];
    const float* bo = (const float*)d_in[8];

    float* out = (float*)d_out;

    const size_t mat  = (size_t)M_TOTAL * D_MODEL;   // 4M elements
    const size_t wmat = (size_t)D_MODEL * D_MODEL;
    unsigned short* xb  = (unsigned short*)d_ws;
    unsigned short* Wqt = xb  + mat;
    unsigned short* Wkt = Wqt + wmat;
    unsigned short* Wvt = Wkt + wmat;
    unsigned short* Wot = Wvt + wmat;
    unsigned short* Qb  = Wot + wmat;
    unsigned short* Kb  = Qb  + mat;
    unsigned short* Vb  = Kb  + mat;
    unsigned short* Ab  = Vb  + mat;
    unsigned short* Op  = Ab  + mat;        // 2 x 8MB
    float2*         ml  = (float2*)d_ws;    // overlay on dead xb, 1MB

    conv_x<<<dim3(2048), 256, 0, stream>>>(x, xb);
    conv_wt<<<dim3(32, 32, 4), 256, 0, stream>>>(Wq, Wk, Wv, Wo, Wqt, Wkt, Wvt, Wot);

    qkv_mfma<<<dim3(8, 32, 3), 256, 0, stream>>>(xb, Wqt, bq, Wkt, bk, Wvt, bv, Qb, Kb, Vb);

    attn_mfma<<<dim3(SEQ / 128, BATCH * NHEADS, NSPLIT), 256, 0, stream>>>(Qb, Kb, Vb, Op, ml);

    attn_combine<<<dim3((BATCH * NHEADS * SEQ * 8) / 256), 256, 0, stream>>>(Op, ml, Ab);

    oproj_mfma<<<dim3(8, 32), 256, 0, stream>>>(Ab, Wot, bo, out);
}